// Round 9
// baseline (179.387 us; speedup 1.0000x reference)
//
#include <hip/hip_runtime.h>

#define STEPS 32768
#define DIO 63
#define HSZ 256
#define NL 6
#define BM 64
#define THREADS 512

// 32x32x16 A-fragment order: frag = 1KB, lane l holds row f=base+(l&31),
// k-slice (l>>5)*8. Bg[l][fb=8][kk16=16][g=3][lane][e], log2e-prescaled.
#define NBGF  (NL * 8 * 16 * 3 * 512)      // 1,179,648 bf16
#define NBIAS (19 * 256)                    // [lg=18: gates i,g,o x 6L | 18: b_in][wi][q][hi][j], f32
#define NBINF (8 * 4 * 512)                 // W_in  [fb][kk16][lane][e], K 63->64
#define NBFCF (2 * 16 * 512)                // W_fc  [ff][kk16][lane][e], feats 63->64

typedef __bf16 bf16_8 __attribute__((ext_vector_type(8)));
typedef __bf16 bf16_4 __attribute__((ext_vector_type(4)));
typedef float f32x4 __attribute__((ext_vector_type(4)));
typedef float f32x16 __attribute__((ext_vector_type(16)));

#define LOG2E  1.4426950408889634f
#define LOG2E2 2.8853900817779268f

__device__ __forceinline__ unsigned short f2bf(float f) {
    unsigned int u = __float_as_uint(f);
    u = u + 0x7fffu + ((u >> 16) & 1u);   // RNE
    return (unsigned short)(u >> 16);
}

__global__ void prep_kernel(const float* __restrict__ W_in,
                            const float* __restrict__ W_ih,
                            const float* __restrict__ b_in,
                            const float* __restrict__ b_ih,
                            const float* __restrict__ b_hh,
                            const float* __restrict__ W_fc,
                            unsigned short* __restrict__ Bg,
                            float* __restrict__ biasF,
                            unsigned short* __restrict__ Bin,
                            unsigned short* __restrict__ Bfc) {
    int idx = blockIdx.x * 256 + threadIdx.x;
    if (idx < NBGF) {
        int e    = idx & 7;
        int lane = (idx >> 3) & 63;
        int rest = idx >> 9;
        int g    = rest % 3;
        int t    = rest / 3;
        int kk   = t & 15;
        int fb   = (t >> 4) & 7;
        int l    = t >> 7;
        int f = fb * 32 + (lane & 31);
        int k = kk * 16 + (lane >> 5) * 8 + e;
        int r = f + (g == 0 ? 0 : (g == 1 ? 512 : 768));   // torch i,f,g,o; f dead
        float sc = (g == 1) ? LOG2E2 : LOG2E;
        Bg[idx] = f2bf(W_ih[((size_t)l * 1024 + r) * HSZ + k] * sc);
        return;
    }
    idx -= NBGF;
    if (idx < NBIAS) {
        int j  = idx & 3;
        int hi = (idx >> 2) & 1;
        int q  = (idx >> 3) & 3;
        int wi = (idx >> 5) & 7;
        int lg = idx >> 8;            // 0..18
        int f = wi * 32 + q * 8 + hi * 4 + j;
        float val;
        if (lg == 18) {
            val = b_in[f];
        } else {
            int l = lg / 3, g = lg % 3;
            int r = f + (g == 0 ? 0 : (g == 1 ? 512 : 768));
            float sc = (g == 1) ? LOG2E2 : LOG2E;
            val = (b_ih[l * 1024 + r] + b_hh[l * 1024 + r]) * sc;
        }
        biasF[idx] = val;
        return;
    }
    idx -= NBIAS;
    if (idx < NBINF) {
        int e = idx & 7, lane = (idx >> 3) & 63, kk = (idx >> 9) & 3, fb = idx >> 11;
        int f = fb * 32 + (lane & 31);
        int k = kk * 16 + (lane >> 5) * 8 + e;
        Bin[idx] = (k < DIO) ? f2bf(W_in[f * DIO + k]) : (unsigned short)0;
        return;
    }
    idx -= NBINF;
    if (idx < NBFCF) {
        int e = idx & 7, lane = (idx >> 3) & 63, kk = (idx >> 9) & 15, ff = idx >> 13;
        int f = ff * 32 + (lane & 31);
        int k = kk * 16 + (lane >> 5) * 8 + e;
        Bfc[idx] = (f < DIO) ? f2bf(W_fc[f * HSZ + k]) : (unsigned short)0;
    }
}

__device__ __forceinline__ f32x16 bias16(const float* pb) {
    f32x4 a = *(const f32x4*)pb;
    f32x4 b = *(const f32x4*)(pb + 8);
    f32x4 c = *(const f32x4*)(pb + 16);
    f32x4 d = *(const f32x4*)(pb + 24);
    f32x16 r;
    r[0]=a[0]; r[1]=a[1]; r[2]=a[2]; r[3]=a[3];
    r[4]=b[0]; r[5]=b[1]; r[6]=b[2]; r[7]=b[3];
    r[8]=c[0]; r[9]=c[1]; r[10]=c[2]; r[11]=c[3];
    r[12]=d[0]; r[13]=d[1]; r[14]=d[2]; r[15]=d[3];
    return r;
}

// write one 32x32 C/D tile (feature rows, step cols) to [kk][lq][s][e] LDS,
// applying f32->bf16. C/D: col(step)=lane&31, row(feat)=(r&3)+8*(r>>2)+4*hi.
__device__ __forceinline__ void write16(char* buf, int wid, int hi, int l31,
                                        int sp, f32x16 v) {
    int base = wid * 4096 + (sp * 32 + l31) * 16 + hi * 8;
#pragma unroll
    for (int q = 0; q < 4; ++q) {
        bf16_4 hv;
#pragma unroll
        for (int j = 0; j < 4; ++j) hv[j] = (__bf16)v[q * 4 + j];
        *(bf16_4*)(buf + base + q * 1024) = hv;
    }
}

// h-act: h = sig(o) * tanh(c), tanh via Pade(3,2) (err<=3e-4 << bf16 rounding)
__device__ __forceinline__ void hact_write(char* buf, int wid, int hi, int l31,
                                           int sp, f32x16 ao, f32x16 cv) {
    int base = wid * 4096 + (sp * 32 + l31) * 16 + hi * 8;
#pragma unroll
    for (int q = 0; q < 4; ++q) {
        bf16_4 hv;
#pragma unroll
        for (int j = 0; j < 4; ++j) {
            int r = q * 4 + j;
            float eo = __builtin_amdgcn_exp2f(ao[r]);
            float c = cv[r];
            float z = c * c;
            float num = eo * c * (z + 15.f);
            float den = (1.f + eo) * fmaf(6.f, z, 15.f);
            hv[j] = (__bf16)(num * __builtin_amdgcn_rcpf(den));
        }
        *(bf16_4*)(buf + base + q * 1024) = hv;
    }
}

// v9: 32x32x16 MFMA (4060 vs 3378 FLOP/cy/CU), operand-swapped (A=W, B=h).
// Per layer per wave (32 feats x 64 steps): pass1 = i,g gates concurrent
// (acc 64 regs), c-act, pass2 = o gate (acc 32, overlaps c-act VALU), h-act.
// Weights read once/layer/wave (48KB); h double-buffered; 1 barrier/layer.
// No clamps: |gate| <= ||Wrow||2*||h||2*log2e2 < 27 -> exp2 safe.
__global__ __launch_bounds__(THREADS, 2) void rnn_fused(
    const float* __restrict__ inp, const float* __restrict__ b_fc,
    const unsigned short* __restrict__ Bg, const float* __restrict__ biasF,
    const unsigned short* __restrict__ Bin, const unsigned short* __restrict__ Bfc,
    float* __restrict__ out) {
    __shared__ __align__(16) unsigned short h_lds[2 * 8 * 4 * 64 * 8];   // 64KB
    unsigned short* in_alias = h_lds + 16384;   // aliases buf1 (dead by layer0 write)

    const int tid = threadIdx.x;
    const int lane = tid & 63;
    const int l31 = lane & 31;
    const int hi = lane >> 5;
    const int wid = tid >> 6;
    const int row0 = blockIdx.x * BM;
    const int vB = hi * 1024 + l31 * 16;   // B-read per-lane base

    // ---- stage input (64 x 63 fp32 -> bf16, K pad 64), [kk32][lq][s][e] ----
    for (int idx = tid; idx < BM * 64; idx += THREADS) {
        int s = idx >> 6, k = idx & 63;
        float v = (k < DIO) ? inp[(size_t)(row0 + s) * DIO + k] : 0.f;
        int off = (k >> 5) * 4096 + ((k >> 3) & 3) * 1024 + s * 16 + (k & 7) * 2;
        *(unsigned short*)((char*)in_alias + off) = f2bf(v);
    }
    __syncthreads();

    // ---- input GEMM: x^T = W_in * inp^T + b_in -> buf0 ----
    {
        const char* pA = (const char*)Bin + lane * 16;
        const char* cin = (const char*)in_alias;
        f32x16 x0 = bias16(biasF + (18 * 8 + wid) * 32 + hi * 4);
        f32x16 x1 = x0;
#pragma unroll
        for (int kk = 0; kk < 4; ++kk) {
            bf16_8 wa = *(const bf16_8*)(pA + (wid * 4 + kk) * 1024);
            bf16_8 b0 = *(const bf16_8*)(cin + vB + (kk >> 1) * 4096 + (kk & 1) * 2048);
            bf16_8 b1 = *(const bf16_8*)(cin + vB + (kk >> 1) * 4096 + (kk & 1) * 2048 + 512);
            x0 = __builtin_amdgcn_mfma_f32_32x32x16_bf16(wa, b0, x0, 0, 0, 0);
            x1 = __builtin_amdgcn_mfma_f32_32x32x16_bf16(wa, b1, x1, 0, 0, 0);
        }
        write16((char*)h_lds, wid, hi, l31, 0, x0);
        write16((char*)h_lds, wid, hi, l31, 1, x1);
    }
    __syncthreads();

    // ---- 6 layers ----
    const char* BgW = (const char*)Bg + (size_t)wid * 49152 + lane * 16;
    for (int l = 0; l < NL; ++l) {
        const char* cur = (const char*)h_lds + (l & 1) * 32768;
        char* nxt = (char*)h_lds + ((l + 1) & 1) * 32768;
        const char* pW = BgW + (size_t)l * 393216;
        const float* pb = biasF + (l * 3 * 8 + wid) * 32 + hi * 4;

        // pass1: i and g gates, both step-halves
        f32x16 ai0 = bias16(pb), ai1 = ai0;
        f32x16 ag0 = bias16(pb + 256), ag1 = ag0;
#pragma unroll
        for (int kk = 0; kk < 16; ++kk) {
            bf16_8 wa = *(const bf16_8*)(pW + (kk * 3 + 0) * 1024);
            bf16_8 wg = *(const bf16_8*)(pW + (kk * 3 + 1) * 1024);
            bf16_8 b0 = *(const bf16_8*)(cur + vB + (kk >> 1) * 4096 + (kk & 1) * 2048);
            bf16_8 b1 = *(const bf16_8*)(cur + vB + (kk >> 1) * 4096 + (kk & 1) * 2048 + 512);
            ai0 = __builtin_amdgcn_mfma_f32_32x32x16_bf16(wa, b0, ai0, 0, 0, 0);
            ai1 = __builtin_amdgcn_mfma_f32_32x32x16_bf16(wa, b1, ai1, 0, 0, 0);
            ag0 = __builtin_amdgcn_mfma_f32_32x32x16_bf16(wg, b0, ag0, 0, 0, 0);
            ag1 = __builtin_amdgcn_mfma_f32_32x32x16_bf16(wg, b1, ag1, 0, 0, 0);
        }
        // c-act: c = sig(i)*tanh(g) = ei*(eg-1)/((1+ei)*(1+eg))
        f32x16 c0, c1;
#pragma unroll
        for (int r = 0; r < 16; ++r) {
            float ei = __builtin_amdgcn_exp2f(ai0[r]);
            float eg = __builtin_amdgcn_exp2f(ag0[r]);
            c0[r] = ei * (eg - 1.f) * __builtin_amdgcn_rcpf((1.f + ei) * (1.f + eg));
            ei = __builtin_amdgcn_exp2f(ai1[r]);
            eg = __builtin_amdgcn_exp2f(ag1[r]);
            c1[r] = ei * (eg - 1.f) * __builtin_amdgcn_rcpf((1.f + ei) * (1.f + eg));
        }
        // pass2: o gate (independent of c-act -> overlaps)
        f32x16 ao0 = bias16(pb + 512), ao1 = ao0;
#pragma unroll
        for (int kk = 0; kk < 16; ++kk) {
            bf16_8 wo = *(const bf16_8*)(pW + (kk * 3 + 2) * 1024);
            bf16_8 b0 = *(const bf16_8*)(cur + vB + (kk >> 1) * 4096 + (kk & 1) * 2048);
            bf16_8 b1 = *(const bf16_8*)(cur + vB + (kk >> 1) * 4096 + (kk & 1) * 2048 + 512);
            ao0 = __builtin_amdgcn_mfma_f32_32x32x16_bf16(wo, b0, ao0, 0, 0, 0);
            ao1 = __builtin_amdgcn_mfma_f32_32x32x16_bf16(wo, b1, ao1, 0, 0, 0);
        }
        hact_write(nxt, wid, hi, l31, 0, ao0, c0);
        hact_write(nxt, wid, hi, l31, 1, ao1, c1);
        __syncthreads();
    }

    // ---- final GEMM: out^T = W_fc * h^T + b_fc (buf0; waves 0-3) ----
    if (wid < 4) {
        const int ff = wid & 1;
        const int sf = wid >> 1;
        const char* pF = (const char*)Bfc + lane * 16;
        const char* cur = (const char*)h_lds;
        f32x16 o;
#pragma unroll
        for (int r = 0; r < 16; ++r) o[r] = 0.f;
#pragma unroll
        for (int kk = 0; kk < 16; ++kk) {
            bf16_8 a = *(const bf16_8*)(pF + (ff * 16 + kk) * 1024);
            bf16_8 b = *(const bf16_8*)(cur + vB + (kk >> 1) * 4096 + (kk & 1) * 2048 + sf * 512);
            o = __builtin_amdgcn_mfma_f32_32x32x16_bf16(a, b, o, 0, 0, 0);
        }
        int s = row0 + sf * 32 + l31;
#pragma unroll
        for (int r = 0; r < 16; ++r) {
            int f = ff * 32 + (r & 3) + 8 * (r >> 2) + 4 * hi;
            if (f < DIO) out[(size_t)s * DIO + f] = o[r] + b_fc[f];
        }
    }
}

extern "C" void kernel_launch(void* const* d_in, const int* in_sizes, int n_in,
                              void* d_out, int out_size, void* d_ws, size_t ws_size,
                              hipStream_t stream) {
    const float* inputs = (const float*)d_in[0];
    const float* W_in   = (const float*)d_in[1];
    const float* b_in   = (const float*)d_in[2];
    const float* W_ih   = (const float*)d_in[3];
    // d_in[4] = W_hh: unused (h_prev == 0 every step)
    const float* b_ih   = (const float*)d_in[5];
    const float* b_hh   = (const float*)d_in[6];
    const float* W_fc   = (const float*)d_in[7];
    const float* b_fc   = (const float*)d_in[8];

    unsigned short* Bg  = (unsigned short*)d_ws;
    float* biasF        = (float*)((char*)d_ws + (size_t)NBGF * 2);
    unsigned short* Bin = (unsigned short*)((char*)biasF + (size_t)NBIAS * 4);
    unsigned short* Bfc = Bin + NBINF;

    int total = NBGF + NBIAS + NBINF + NBFCF;
    prep_kernel<<<(total + 255) / 256, 256, 0, stream>>>(W_in, W_ih, b_in, b_ih, b_hh,
                                                         W_fc, Bg, biasF, Bin, Bfc);
    rnn_fused<<<STEPS / BM, THREADS, 0, stream>>>(inputs, b_fc, Bg, biasF, Bin, Bfc,
                                                  (float*)d_out);
}

// Round 10
// 116.917 us; speedup vs baseline: 1.5343x; 1.5343x over previous
//
#include <hip/hip_runtime.h>

#define STEPS 32768
#define DIO 63
#define HSZ 256
#define NL 6
#define BM 64
#define THREADS 512

// 32x32x16 A-fragment order: frag = 1KB, lane l holds row f=base+(l&31),
// k-slice (l>>5)*8. Bg[l][fb=8][kk16=16][g=3][lane][e], log2e-prescaled.
#define NBGF  (NL * 8 * 16 * 3 * 512)      // 1,179,648 bf16
#define NBIAS (19 * 256)                    // [lg: 18 gate-sets | b_in][wi][q][hi][j], f32
#define NBINF (8 * 4 * 512)                 // W_in  [fb][kk16][lane][e], K 63->64
#define NBFCF (2 * 16 * 512)                // W_fc  [ff][kk16][lane][e], feats 63->64

typedef __bf16 bf16_8 __attribute__((ext_vector_type(8)));
typedef __bf16 bf16_4 __attribute__((ext_vector_type(4)));
typedef float f32x4 __attribute__((ext_vector_type(4)));
typedef float f32x16 __attribute__((ext_vector_type(16)));

#define LOG2E  1.4426950408889634f
#define LOG2E2 2.8853900817779268f

__device__ __forceinline__ unsigned short f2bf(float f) {
    unsigned int u = __float_as_uint(f);
    u = u + 0x7fffu + ((u >> 16) & 1u);   // RNE
    return (unsigned short)(u >> 16);
}

__global__ void prep_kernel(const float* __restrict__ W_in,
                            const float* __restrict__ W_ih,
                            const float* __restrict__ b_in,
                            const float* __restrict__ b_ih,
                            const float* __restrict__ b_hh,
                            const float* __restrict__ W_fc,
                            unsigned short* __restrict__ Bg,
                            float* __restrict__ biasF,
                            unsigned short* __restrict__ Bin,
                            unsigned short* __restrict__ Bfc) {
    int idx = blockIdx.x * 256 + threadIdx.x;
    if (idx < NBGF) {
        int e    = idx & 7;
        int lane = (idx >> 3) & 63;
        int rest = idx >> 9;
        int g    = rest % 3;
        int t    = rest / 3;
        int kk   = t & 15;
        int fb   = (t >> 4) & 7;
        int l    = t >> 7;
        int f = fb * 32 + (lane & 31);
        int k = kk * 16 + (lane >> 5) * 8 + e;
        int r = f + (g == 0 ? 0 : (g == 1 ? 512 : 768));   // torch i,f,g,o; f dead
        float sc = (g == 1) ? LOG2E2 : LOG2E;
        Bg[idx] = f2bf(W_ih[((size_t)l * 1024 + r) * HSZ + k] * sc);
        return;
    }
    idx -= NBGF;
    if (idx < NBIAS) {
        int j  = idx & 3;
        int hi = (idx >> 2) & 1;
        int q  = (idx >> 3) & 3;
        int wi = (idx >> 5) & 7;
        int lg = idx >> 8;            // 0..18
        int f = wi * 32 + q * 8 + hi * 4 + j;
        float val;
        if (lg == 18) {
            val = b_in[f];
        } else {
            int l = lg / 3, g = lg % 3;
            int r = f + (g == 0 ? 0 : (g == 1 ? 512 : 768));
            float sc = (g == 1) ? LOG2E2 : LOG2E;
            val = (b_ih[l * 1024 + r] + b_hh[l * 1024 + r]) * sc;
        }
        biasF[idx] = val;
        return;
    }
    idx -= NBIAS;
    if (idx < NBINF) {
        int e = idx & 7, lane = (idx >> 3) & 63, kk = (idx >> 9) & 3, fb = idx >> 11;
        int f = fb * 32 + (lane & 31);
        int k = kk * 16 + (lane >> 5) * 8 + e;
        Bin[idx] = (k < DIO) ? f2bf(W_in[f * DIO + k]) : (unsigned short)0;
        return;
    }
    idx -= NBINF;
    if (idx < NBFCF) {
        int e = idx & 7, lane = (idx >> 3) & 63, kk = (idx >> 9) & 15, ff = idx >> 13;
        int f = ff * 32 + (lane & 31);
        int k = kk * 16 + (lane >> 5) * 8 + e;
        Bfc[idx] = (f < DIO) ? f2bf(W_fc[f * HSZ + k]) : (unsigned short)0;
    }
}

__device__ __forceinline__ f32x16 bias16(const float* pb) {
    f32x4 a = *(const f32x4*)pb;
    f32x4 b = *(const f32x4*)(pb + 8);
    f32x4 c = *(const f32x4*)(pb + 16);
    f32x4 d = *(const f32x4*)(pb + 24);
    f32x16 r;
    r[0]=a[0]; r[1]=a[1]; r[2]=a[2]; r[3]=a[3];
    r[4]=b[0]; r[5]=b[1]; r[6]=b[2]; r[7]=b[3];
    r[8]=c[0]; r[9]=c[1]; r[10]=c[2]; r[11]=c[3];
    r[12]=d[0]; r[13]=d[1]; r[14]=d[2]; r[15]=d[3];
    return r;
}

// write one 32x32 C/D tile (feature rows, step cols) to [kk][lq][s][e] LDS.
// C/D: col(step)=lane&31, row(feat)=(r&3)+8*(r>>2)+4*hi.
__device__ __forceinline__ void write16(char* buf, int wid, int hi, int l31,
                                        int sp, f32x16 v) {
    int base = wid * 4096 + (sp * 32 + l31) * 16 + hi * 8;
#pragma unroll
    for (int q = 0; q < 4; ++q) {
        bf16_4 hv;
#pragma unroll
        for (int j = 0; j < 4; ++j) hv[j] = (__bf16)v[q * 4 + j];
        *(bf16_4*)(buf + base + q * 1024) = hv;
    }
}

// full LSTM act: c = sig(i)*tanh(g), h = sig(o)*tanh(c) (Pade(3,2), err<=3e-4)
__device__ __forceinline__ void gate_write(char* buf, int wid, int hi, int l31,
                                           int sp, f32x16 ai, f32x16 ag, f32x16 ao) {
    int base = wid * 4096 + (sp * 32 + l31) * 16 + hi * 8;
#pragma unroll
    for (int q = 0; q < 4; ++q) {
        bf16_4 hv;
#pragma unroll
        for (int j = 0; j < 4; ++j) {
            int r = q * 4 + j;
            float ei = __builtin_amdgcn_exp2f(ai[r]);
            float eg = __builtin_amdgcn_exp2f(ag[r]);
            float eo = __builtin_amdgcn_exp2f(ao[r]);
            float c = ei * (eg - 1.f) *
                      __builtin_amdgcn_rcpf((1.f + ei) * (1.f + eg));
            float z = c * c;
            hv[j] = (__bf16)(eo * c * (z + 15.f) *
                             __builtin_amdgcn_rcpf((1.f + eo) * fmaf(6.f, z, 15.f)));
        }
        *(bf16_4*)(buf + base + q * 1024) = hv;
    }
}

// v10: 32x32x16 MFMA, operand-swapped (A=W, B=h), ALL 3 gates concurrent in ONE
// pass per layer -> 6 independent MFMA chains (dep distance 48cy >= latency),
// B-tile read ONCE per wave-layer (32KB, half of v8), weights once (48KB,
// redundancy-1), 1 barrier/layer, single act phase.
// VGPR budget: 96 acc + 12 w + 8 b + ~10 addr ~ 126 <= 128 cap at (512,2).
// Spill sentinel: WRITE_SIZE (8MB clean; >>10MB means regalloc failed).
__global__ __launch_bounds__(THREADS, 2) void rnn_fused(
    const float* __restrict__ inp, const float* __restrict__ b_fc,
    const unsigned short* __restrict__ Bg, const float* __restrict__ biasF,
    const unsigned short* __restrict__ Bin, const unsigned short* __restrict__ Bfc,
    float* __restrict__ out) {
    __shared__ __align__(16) unsigned short h_lds[2 * 8 * 4 * 64 * 8];   // 64KB
    unsigned short* in_alias = h_lds + 16384;   // aliases buf1 (dead by layer0 write)

    const int tid = threadIdx.x;
    const int lane = tid & 63;
    const int l31 = lane & 31;
    const int hi = lane >> 5;
    const int wid = tid >> 6;
    const int row0 = blockIdx.x * BM;
    const int vB = hi * 1024 + l31 * 16;   // B-read per-lane base

    // ---- stage input (64 x 63 fp32 -> bf16, K pad 64), [kk32][lq][s][e] ----
    for (int idx = tid; idx < BM * 64; idx += THREADS) {
        int s = idx >> 6, k = idx & 63;
        float v = (k < DIO) ? inp[(size_t)(row0 + s) * DIO + k] : 0.f;
        int off = (k >> 5) * 4096 + ((k >> 3) & 3) * 1024 + s * 16 + (k & 7) * 2;
        *(unsigned short*)((char*)in_alias + off) = f2bf(v);
    }
    __syncthreads();

    // ---- input GEMM: x^T = W_in * inp^T + b_in -> buf0 ----
    {
        const char* pA = (const char*)Bin + lane * 16;
        const char* cin = (const char*)in_alias;
        f32x16 x0 = bias16(biasF + (18 * 8 + wid) * 32 + hi * 4);
        f32x16 x1 = x0;
#pragma unroll
        for (int kk = 0; kk < 4; ++kk) {
            bf16_8 wa = *(const bf16_8*)(pA + (wid * 4 + kk) * 1024);
            bf16_8 b0 = *(const bf16_8*)(cin + vB + (kk >> 1) * 4096 + (kk & 1) * 2048);
            bf16_8 b1 = *(const bf16_8*)(cin + vB + (kk >> 1) * 4096 + (kk & 1) * 2048 + 512);
            x0 = __builtin_amdgcn_mfma_f32_32x32x16_bf16(wa, b0, x0, 0, 0, 0);
            x1 = __builtin_amdgcn_mfma_f32_32x32x16_bf16(wa, b1, x1, 0, 0, 0);
        }
        write16((char*)h_lds, wid, hi, l31, 0, x0);
        write16((char*)h_lds, wid, hi, l31, 1, x1);
    }
    __syncthreads();

    // ---- 6 layers: one fused pass, 6 concurrent MFMA chains ----
    const char* BgW = (const char*)Bg + (size_t)wid * 49152 + lane * 16;
    for (int l = 0; l < NL; ++l) {
        const char* cur = (const char*)h_lds + (l & 1) * 32768;
        char* nxt = (char*)h_lds + ((l + 1) & 1) * 32768;
        const char* pW = BgW + (size_t)l * 393216;
        const float* pb = biasF + (l * 24 + wid) * 32 + hi * 4;

        f32x16 ai0 = bias16(pb), ai1 = ai0;
        f32x16 ag0 = bias16(pb + 256), ag1 = ag0;
        f32x16 ao0 = bias16(pb + 512), ao1 = ao0;
#pragma unroll
        for (int kk = 0; kk < 16; ++kk) {
            bf16_8 wa = *(const bf16_8*)(pW + kk * 3072);
            bf16_8 wg = *(const bf16_8*)(pW + kk * 3072 + 1024);
            bf16_8 wo = *(const bf16_8*)(pW + kk * 3072 + 2048);
            bf16_8 b0 = *(const bf16_8*)(cur + vB + (kk >> 1) * 4096 + (kk & 1) * 2048);
            bf16_8 b1 = *(const bf16_8*)(cur + vB + (kk >> 1) * 4096 + (kk & 1) * 2048 + 512);
            ai0 = __builtin_amdgcn_mfma_f32_32x32x16_bf16(wa, b0, ai0, 0, 0, 0);
            ag0 = __builtin_amdgcn_mfma_f32_32x32x16_bf16(wg, b0, ag0, 0, 0, 0);
            ao0 = __builtin_amdgcn_mfma_f32_32x32x16_bf16(wo, b0, ao0, 0, 0, 0);
            ai1 = __builtin_amdgcn_mfma_f32_32x32x16_bf16(wa, b1, ai1, 0, 0, 0);
            ag1 = __builtin_amdgcn_mfma_f32_32x32x16_bf16(wg, b1, ag1, 0, 0, 0);
            ao1 = __builtin_amdgcn_mfma_f32_32x32x16_bf16(wo, b1, ao1, 0, 0, 0);
        }
        gate_write(nxt, wid, hi, l31, 0, ai0, ag0, ao0);
        gate_write(nxt, wid, hi, l31, 1, ai1, ag1, ao1);
        __syncthreads();
    }

    // ---- final GEMM: out^T = W_fc * h^T + b_fc (buf0; waves 0-3) ----
    if (wid < 4) {
        const int ff = wid & 1;
        const int sf = wid >> 1;
        const char* pF = (const char*)Bfc + lane * 16;
        const char* cur = (const char*)h_lds;
        f32x16 o;
#pragma unroll
        for (int r = 0; r < 16; ++r) o[r] = 0.f;
#pragma unroll
        for (int kk = 0; kk < 16; ++kk) {
            bf16_8 a = *(const bf16_8*)(pF + (ff * 16 + kk) * 1024);
            bf16_8 b = *(const bf16_8*)(cur + vB + (kk >> 1) * 4096 + (kk & 1) * 2048 + sf * 512);
            o = __builtin_amdgcn_mfma_f32_32x32x16_bf16(a, b, o, 0, 0, 0);
        }
        int s = row0 + sf * 32 + l31;
#pragma unroll
        for (int r = 0; r < 16; ++r) {
            int f = ff * 32 + (r & 3) + 8 * (r >> 2) + 4 * hi;
            if (f < DIO) out[(size_t)s * DIO + f] = o[r] + b_fc[f];
        }
    }
}

extern "C" void kernel_launch(void* const* d_in, const int* in_sizes, int n_in,
                              void* d_out, int out_size, void* d_ws, size_t ws_size,
                              hipStream_t stream) {
    const float* inputs = (const float*)d_in[0];
    const float* W_in   = (const float*)d_in[1];
    const float* b_in   = (const float*)d_in[2];
    const float* W_ih   = (const float*)d_in[3];
    // d_in[4] = W_hh: unused (h_prev == 0 every step)
    const float* b_ih   = (const float*)d_in[5];
    const float* b_hh   = (const float*)d_in[6];
    const float* W_fc   = (const float*)d_in[7];
    const float* b_fc   = (const float*)d_in[8];

    unsigned short* Bg  = (unsigned short*)d_ws;
    float* biasF        = (float*)((char*)d_ws + (size_t)NBGF * 2);
    unsigned short* Bin = (unsigned short*)((char*)biasF + (size_t)NBIAS * 4);
    unsigned short* Bfc = Bin + NBINF;

    int total = NBGF + NBIAS + NBINF + NBFCF;
    prep_kernel<<<(total + 255) / 256, 256, 0, stream>>>(W_in, W_ih, b_in, b_ih, b_hh,
                                                         W_fc, Bg, biasF, Bin, Bfc);
    rnn_fused<<<STEPS / BM, THREADS, 0, stream>>>(inputs, b_fc, Bg, biasF, Bin, Bfc,
                                                  (float*)d_out);
}

// Round 11
// 115.189 us; speedup vs baseline: 1.5573x; 1.0150x over previous
//
#include <hip/hip_runtime.h>

#define STEPS 32768
#define DIO 63
#define HSZ 256
#define NL 6
#define BM 64
#define THREADS 512

// Gate weights, A-role fragment order, grouped per (layer, pass, wave, kk):
// Bg[(((((l*2+p)*8+wid)*8+kk)*3+g)*64 + lane)*8 + e], bf16, log2e-prescaled.
#define NBGF  (NL * 2 * 8 * 8 * 3 * 512)   // 1,179,648 bf16
#define NBIAS (NL * 768)                    // fused (b_ih+b_hh)*scale, f32, [l][g][256]
#define NBINF (16 * 2 * 64 * 8)             // W_in  [fb][kk][lane][e], K 63->64
#define NBFCF (4 * 8 * 64 * 8)              // W_fc  [fm][kk][lane][e]

typedef __bf16 bf16_8 __attribute__((ext_vector_type(8)));
typedef __bf16 bf16_4 __attribute__((ext_vector_type(4)));
typedef float f32x4 __attribute__((ext_vector_type(4)));

#define LOG2E  1.4426950408889634f
#define LOG2E2 2.8853900817779268f

__device__ __forceinline__ unsigned short f2bf(float f) {
    unsigned int u = __float_as_uint(f);
    u = u + 0x7fffu + ((u >> 16) & 1u);   // RNE
    return (unsigned short)(u >> 16);
}

__global__ void prep_kernel(const float* __restrict__ W_in,
                            const float* __restrict__ W_ih,
                            const float* __restrict__ b_ih,
                            const float* __restrict__ b_hh,
                            const float* __restrict__ W_fc,
                            unsigned short* __restrict__ Bg,
                            float* __restrict__ bias,
                            unsigned short* __restrict__ Bin,
                            unsigned short* __restrict__ Bfc) {
    int idx = blockIdx.x * 256 + threadIdx.x;
    if (idx < NBGF) {
        int e    = idx & 7;
        int lane = (idx >> 3) & 63;
        int t    = idx >> 9;       // (((l*2+p)*8+w)*8+kk)*3+g
        int g    = t % 3;
        int u    = t / 3;
        int kk   = u & 7;
        int v    = u >> 3;
        int w    = v & 7;
        int x    = v >> 3;
        int p    = x & 1;
        int l    = x >> 1;
        int f = (p * 8 + w) * 16 + (lane & 15);
        int k = kk * 32 + (lane >> 4) * 8 + e;
        int r = f + (g == 0 ? 0 : (g == 1 ? 512 : 768));   // torch i,f,g,o; f dead
        float sc = (g == 1) ? LOG2E2 : LOG2E;
        Bg[idx] = f2bf(W_ih[((size_t)l * 1024 + r) * HSZ + k] * sc);
        return;
    }
    idx -= NBGF;
    if (idx < NBIAS) {
        int j = idx % 768, l = idx / 768;
        int g = j >> 8;
        int r = (j < 256) ? j : j + 256;
        float sc = (g == 1) ? LOG2E2 : LOG2E;
        bias[idx] = (b_ih[l * 1024 + r] + b_hh[l * 1024 + r]) * sc;
        return;
    }
    idx -= NBIAS;
    if (idx < NBINF) {
        int e = idx & 7, lane = (idx >> 3) & 63, kk = (idx >> 9) & 1, fb = idx >> 10;
        int f = fb * 16 + (lane & 15);
        int k = kk * 32 + (lane >> 4) * 8 + e;
        Bin[idx] = (k < DIO) ? f2bf(W_in[f * DIO + k]) : (unsigned short)0;
        return;
    }
    idx -= NBINF;
    if (idx < NBFCF) {
        int e = idx & 7, lane = (idx >> 3) & 63, kk = (idx >> 9) & 7, fm = idx >> 12;
        int f = fm * 16 + (lane & 15);
        int k = kk * 32 + (lane >> 4) * 8 + e;
        Bfc[idx] = (f < DIO) ? f2bf(W_fc[f * HSZ + k]) : (unsigned short)0;
    }
}

__device__ __forceinline__ void ld3(const char* p, bf16_8& a, bf16_8& g, bf16_8& o) {
    a = *(const bf16_8*)(p);
    g = *(const bf16_8*)(p + 1024);
    o = *(const bf16_8*)(p + 2048);
}

// one pass: 16 feats x 64 steps, 3 gates concurrent (12 independent MFMA chains).
// wa0/wg0/wo0 arrive preloaded for kk=0; on exit they hold the NEXT pass's kk=0
// weights (loads issued at kk=7, in flight through act+write+barrier).
__device__ __forceinline__ void gate_pass(
    const char* pW, const char* pNext,
    bf16_8& wa0, bf16_8& wg0, bf16_8& wo0,
    const char* cur, int rdB, const float* pb,
    f32x4 (&ai)[4], f32x4 (&ag)[4], f32x4 (&ao)[4]) {
    f32x4 bi4 = *(const f32x4*)(pb);
    f32x4 bg4 = *(const f32x4*)(pb + 256);
    f32x4 bo4 = *(const f32x4*)(pb + 512);
#pragma unroll
    for (int n = 0; n < 4; ++n) { ai[n] = bi4; ag[n] = bg4; ao[n] = bo4; }
    bf16_8 wa = wa0, wg = wg0, wo = wo0;
#pragma unroll
    for (int kk = 0; kk < 8; ++kk) {
        bf16_8 na, ng, no;
        if (kk < 7) ld3(pW + (kk + 1) * 3072, na, ng, no);   // 2-deep prefetch
        else        ld3(pNext, na, ng, no);                  // cross-pass preload
        bf16_8 b[4];
#pragma unroll
        for (int n = 0; n < 4; ++n)
            b[n] = *(const bf16_8*)(cur + rdB + kk * 4096 + n * 256);
#pragma unroll
        for (int n = 0; n < 4; ++n) {
            ai[n] = __builtin_amdgcn_mfma_f32_16x16x32_bf16(wa, b[n], ai[n], 0, 0, 0);
            ag[n] = __builtin_amdgcn_mfma_f32_16x16x32_bf16(wg, b[n], ag[n], 0, 0, 0);
            ao[n] = __builtin_amdgcn_mfma_f32_16x16x32_bf16(wo, b[n], ao[n], 0, 0, 0);
        }
        wa = na; wg = ng; wo = no;
    }
    wa0 = wa; wg0 = wg; wo0 = wo;
}

// act: c = sig(i)*tanh(g); h = sig(o)*tanh(c), tanh Pade(3,2) (err<=3e-4).
// No clamps (v10-proven safe on this data). Packed b64 writes.
__device__ __forceinline__ void act_write(char* nxt, int fb, int lq, int l15,
                                          f32x4 (&ai)[4], f32x4 (&ag)[4], f32x4 (&ao)[4]) {
    const int wrp = (fb >> 1) * 4096 + ((fb & 1) * 2 + (lq >> 1)) * 1024 +
                    l15 * 16 + (lq & 1) * 8;
#pragma unroll
    for (int n = 0; n < 4; ++n) {
        bf16_4 hv;
#pragma unroll
        for (int r = 0; r < 4; ++r) {
            float ei = __builtin_amdgcn_exp2f(ai[n][r]);
            float eg = __builtin_amdgcn_exp2f(ag[n][r]);
            float eo = __builtin_amdgcn_exp2f(ao[n][r]);
            float c = ei * (eg - 1.f) *
                      __builtin_amdgcn_rcpf((1.f + ei) * (1.f + eg));
            float z = c * c;
            hv[r] = (__bf16)(eo * c * (z + 15.f) *
                             __builtin_amdgcn_rcpf((1.f + eo) * fmaf(6.f, z, 15.f)));
        }
        *(bf16_4*)(nxt + wrp + n * 256) = hv;
    }
}

// v11 = v8 structure (16x16, 2 staggered passes/layer, 12 chains, 1 barrier/layer)
// + explicit 2-deep weight prefetch + cross-pass kk0 preload (T14 issue-early)
// + lean act + in_lds aliased into h buf1 (64KB LDS).
__global__ __launch_bounds__(THREADS, 2) void rnn_fused(
    const float* __restrict__ inp, const float* __restrict__ b_in,
    const float* __restrict__ b_fc,
    const unsigned short* __restrict__ Bg, const float* __restrict__ bias,
    const unsigned short* __restrict__ Bin, const unsigned short* __restrict__ Bfc,
    float* __restrict__ out) {
    __shared__ __align__(16) unsigned short h_lds[2 * 8 * 4 * 64 * 8];   // 64KB
    unsigned short* in_alias = h_lds + 16384;   // buf1; dead once layer0 writes

    const int tid = threadIdx.x;
    const int lane = tid & 63;
    const int l15 = lane & 15;
    const int lq = lane >> 4;
    const int wid = tid >> 6;
    const int row0 = blockIdx.x * BM;
    const int rdB = lq * 1024 + l15 * 16;   // one base for all B-role LDS reads

    const char* Wb = (const char*)Bg + lane * 16;
    const int pA = wid & 1, pB = 1 - pA;    // stagger pass order by wave parity

    // preload layer0 first-pass kk=0 weights (independent of input staging)
    bf16_8 wa0, wg0, wo0;
    ld3(Wb + (size_t)(pA * 8 + wid) * 24576, wa0, wg0, wo0);

    // ---- stage input (64 x 63 fp32 -> bf16, K pad 64), [kk][lq][s][e] ----
    for (int idx = tid; idx < BM * 64; idx += THREADS) {
        int s = idx >> 6, k = idx & 63;
        float v = (k < DIO) ? inp[(size_t)(row0 + s) * DIO + k] : 0.f;
        int off = (k >> 5) * 4096 + ((k >> 3) & 3) * 1024 + s * 16 + (k & 7) * 2;
        *(unsigned short*)((char*)in_alias + off) = f2bf(v);
    }
    __syncthreads();

    // ---- input GEMM: x^T = W_in * inp^T + b_in -> buf0 ----
    {
        f32x4 acc[2][4];
#pragma unroll
        for (int m = 0; m < 2; ++m) {
            f32x4 b4 = *(const f32x4*)(b_in + (2 * wid + m) * 16 + lq * 4);
#pragma unroll
            for (int n = 0; n < 4; ++n) acc[m][n] = b4;
        }
        const bf16_8* __restrict__ pIA = (const bf16_8*)Bin + lane;
#pragma unroll
        for (int kk = 0; kk < 2; ++kk) {
            bf16_8 a[2], b[4];
#pragma unroll
            for (int m = 0; m < 2; ++m) a[m] = pIA[((2 * wid + m) * 2 + kk) * 64];
#pragma unroll
            for (int n = 0; n < 4; ++n)
                b[n] = *(const bf16_8*)((const char*)in_alias + rdB + kk * 4096 + n * 256);
#pragma unroll
            for (int m = 0; m < 2; ++m)
#pragma unroll
                for (int n = 0; n < 4; ++n)
                    acc[m][n] = __builtin_amdgcn_mfma_f32_16x16x32_bf16(a[m], b[n], acc[m][n], 0, 0, 0);
        }
#pragma unroll
        for (int m = 0; m < 2; ++m) {
            int wb = wid * 4096 + (2 * m + (lq >> 1)) * 1024 + l15 * 16 + (lq & 1) * 8;
#pragma unroll
            for (int n = 0; n < 4; ++n) {
                bf16_4 hv;
#pragma unroll
                for (int r = 0; r < 4; ++r) hv[r] = (__bf16)acc[m][n][r];
                *(bf16_4*)((char*)h_lds + wb + n * 256) = hv;
            }
        }
    }
    __syncthreads();

    // ---- 6 layers: two staggered passes, 3 gates concurrent each ----
    for (int l = 0; l < NL; ++l) {
        const char* cur = (const char*)h_lds + (l & 1) * 32768;
        char* nxt = (char*)h_lds + ((l + 1) & 1) * 32768;
        const char* pWA = Wb + (size_t)((l * 2 + pA) * 8 + wid) * 24576;
        const char* pWB = Wb + (size_t)((l * 2 + pB) * 8 + wid) * 24576;
        const char* pWN = (l < NL - 1)
            ? Wb + (size_t)(((l + 1) * 2 + pA) * 8 + wid) * 24576
            : pWB;   // harmless dummy preload on last layer
        const float* bl = bias + l * 768 + lq * 4;

        f32x4 ai[4], ag[4], ao[4];
        gate_pass(pWA, pWB, wa0, wg0, wo0, cur, rdB,
                  bl + (pA * 8 + wid) * 16, ai, ag, ao);
        act_write(nxt, pA * 8 + wid, lq, l15, ai, ag, ao);
        gate_pass(pWB, pWN, wa0, wg0, wo0, cur, rdB,
                  bl + (pB * 8 + wid) * 16, ai, ag, ao);
        act_write(nxt, pB * 8 + wid, lq, l15, ai, ag, ao);
        __syncthreads();   // nxt published; cur free
    }

    // ---- final GEMM: out^T = W_fc * h^T + b_fc (h in buf0, NL even) ----
    {
        const char* cur = (const char*)h_lds;
        const int fm = wid & 3;             // feature frag (16 feats)
        const int sb = (wid >> 2) * 2;      // step frags sb, sb+1
        f32x4 o4[2];
#pragma unroll
        for (int n = 0; n < 2; ++n) o4[n] = (f32x4){0.f, 0.f, 0.f, 0.f};
        const bf16_8* __restrict__ pF = (const bf16_8*)Bfc + lane;
#pragma unroll
        for (int kk = 0; kk < 8; ++kk) {
            bf16_8 a = pF[(fm * 8 + kk) * 64];
#pragma unroll
            for (int n = 0; n < 2; ++n) {
                bf16_8 b = *(const bf16_8*)(cur + rdB + kk * 4096 + (sb + n) * 256);
                o4[n] = __builtin_amdgcn_mfma_f32_16x16x32_bf16(a, b, o4[n], 0, 0, 0);
            }
        }
#pragma unroll
        for (int n = 0; n < 2; ++n) {
            int s = row0 + (sb + n) * 16 + l15;
#pragma unroll
            for (int r = 0; r < 4; ++r) {
                int f = fm * 16 + lq * 4 + r;
                if (f < DIO) out[(size_t)s * DIO + f] = o4[n][r] + b_fc[f];
            }
        }
    }
}

extern "C" void kernel_launch(void* const* d_in, const int* in_sizes, int n_in,
                              void* d_out, int out_size, void* d_ws, size_t ws_size,
                              hipStream_t stream) {
    const float* inputs = (const float*)d_in[0];
    const float* W_in   = (const float*)d_in[1];
    const float* b_in   = (const float*)d_in[2];
    const float* W_ih   = (const float*)d_in[3];
    // d_in[4] = W_hh: unused (h_prev == 0 every step)
    const float* b_ih   = (const float*)d_in[5];
    const float* b_hh   = (const float*)d_in[6];
    const float* W_fc   = (const float*)d_in[7];
    const float* b_fc   = (const float*)d_in[8];

    unsigned short* Bg  = (unsigned short*)d_ws;
    float* bias         = (float*)((char*)d_ws + (size_t)NBGF * 2);
    unsigned short* Bin = (unsigned short*)((char*)bias + (size_t)NBIAS * 4);
    unsigned short* Bfc = Bin + NBINF;

    int total = NBGF + NBIAS + NBINF + NBFCF;
    prep_kernel<<<(total + 255) / 256, 256, 0, stream>>>(W_in, W_ih, b_ih, b_hh, W_fc,
                                                         Bg, bias, Bin, Bfc);
    rnn_fused<<<STEPS / BM, THREADS, 0, stream>>>(inputs, b_in, b_fc, Bg, bias, Bin, Bfc,
                                                  (float*)d_out);
}

// Round 12
// 99.246 us; speedup vs baseline: 1.8075x; 1.1606x over previous
//
#include <hip/hip_runtime.h>

#define STEPS 32768
#define DIO 63
#define HSZ 256
#define NL 6
#define BM 64
#define THREADS 1024

// Gate weights, A-role fragment order, grouped per (layer, wave, kk):
// Bg[((((l*16+w)*8+kk)*3+g)*64 + lane)*8 + e], bf16, log2e-prescaled.
#define NBGF  (NL * 16 * 8 * 3 * 512)      // 1,179,648 bf16
#define NBIAS (NL * 768)                    // fused (b_ih+b_hh)*scale, f32, [l][g][256]
#define NBINF (16 * 2 * 64 * 8)             // W_in  [fb][kk][lane][e], K 63->64
#define NBFCF (4 * 8 * 64 * 8)              // W_fc  [ff][kk][lane][e]

typedef __bf16 bf16_8 __attribute__((ext_vector_type(8)));
typedef __bf16 bf16_4 __attribute__((ext_vector_type(4)));
typedef float f32x4 __attribute__((ext_vector_type(4)));

#define LOG2E  1.4426950408889634f
#define LOG2E2 2.8853900817779268f

__device__ __forceinline__ unsigned short f2bf(float f) {
    unsigned int u = __float_as_uint(f);
    u = u + 0x7fffu + ((u >> 16) & 1u);   // RNE
    return (unsigned short)(u >> 16);
}

__global__ void prep_kernel(const float* __restrict__ W_in,
                            const float* __restrict__ W_ih,
                            const float* __restrict__ b_ih,
                            const float* __restrict__ b_hh,
                            const float* __restrict__ W_fc,
                            unsigned short* __restrict__ Bg,
                            float* __restrict__ bias,
                            unsigned short* __restrict__ Bin,
                            unsigned short* __restrict__ Bfc) {
    int idx = blockIdx.x * 256 + threadIdx.x;
    if (idx < NBGF) {
        int e    = idx & 7;
        int lane = (idx >> 3) & 63;
        int t    = idx >> 9;       // ((l*16+w)*8+kk)*3+g
        int g    = t % 3;
        int u    = t / 3;
        int kk   = u & 7;
        int v    = u >> 3;
        int w    = v & 15;
        int l    = v >> 4;
        int f = w * 16 + (lane & 15);
        int k = kk * 32 + (lane >> 4) * 8 + e;
        int r = f + (g == 0 ? 0 : (g == 1 ? 512 : 768));   // torch i,f,g,o; f dead
        float sc = (g == 1) ? LOG2E2 : LOG2E;
        Bg[idx] = f2bf(W_ih[((size_t)l * 1024 + r) * HSZ + k] * sc);
        return;
    }
    idx -= NBGF;
    if (idx < NBIAS) {
        int j = idx % 768, l = idx / 768;
        int g = j >> 8;
        int r = (j < 256) ? j : j + 256;
        float sc = (g == 1) ? LOG2E2 : LOG2E;
        bias[idx] = (b_ih[l * 1024 + r] + b_hh[l * 1024 + r]) * sc;
        return;
    }
    idx -= NBIAS;
    if (idx < NBINF) {
        int e = idx & 7, lane = (idx >> 3) & 63, kk = (idx >> 9) & 1, fb = idx >> 10;
        int f = fb * 16 + (lane & 15);
        int k = kk * 32 + (lane >> 4) * 8 + e;
        Bin[idx] = (k < DIO) ? f2bf(W_in[f * DIO + k]) : (unsigned short)0;
        return;
    }
    idx -= NBINF;
    if (idx < NBFCF) {
        int e = idx & 7, lane = (idx >> 3) & 63, kk = (idx >> 9) & 7, ff = idx >> 12;
        int f = ff * 16 + (lane & 15);
        int k = kk * 32 + (lane >> 4) * 8 + e;
        Bfc[idx] = (f < DIO) ? f2bf(W_fc[f * HSZ + k]) : (unsigned short)0;
    }
}

// act: c = sig(i)*tanh(g); h = sig(o)*tanh(c), tanh Pade(3,2) (err<=3e-4).
// No clamps (v10/v11-proven safe). Packed b64 writes.
__device__ __forceinline__ void act_write(char* nxt, int fb, int lq, int l15,
                                          f32x4 (&ai)[4], f32x4 (&ag)[4], f32x4 (&ao)[4]) {
    const int wrp = (fb >> 1) * 4096 + ((fb & 1) * 2 + (lq >> 1)) * 1024 +
                    l15 * 16 + (lq & 1) * 8;
#pragma unroll
    for (int n = 0; n < 4; ++n) {
        bf16_4 hv;
#pragma unroll
        for (int r = 0; r < 4; ++r) {
            float ei = __builtin_amdgcn_exp2f(ai[n][r]);
            float eg = __builtin_amdgcn_exp2f(ag[n][r]);
            float eo = __builtin_amdgcn_exp2f(ao[n][r]);
            float c = ei * (eg - 1.f) *
                      __builtin_amdgcn_rcpf((1.f + ei) * (1.f + eg));
            float z = c * c;
            hv[r] = (__bf16)(eo * c * (z + 15.f) *
                             __builtin_amdgcn_rcpf((1.f + eo) * fmaf(6.f, z, 15.f)));
        }
        *(bf16_4*)(nxt + wrp + n * 256) = hv;
    }
}

// v12 = v8 per-wave loop, but 16 waves/block (each wave = ONE 16-feat pass) ->
// 2 blocks x 16 waves = 32 waves/CU (8/SIMD), double v8's TLP. Weight
// redundancy still 1; 1 barrier/layer; plain in-loop loads (v11's manual
// prefetch regressed -> compiler schedules). launch_bounds cap law: 256/4=64
// VGPR >= v8's measured 52 demand. Spill sentinel: WRITE_SIZE (~8MB clean).
__global__ __launch_bounds__(THREADS, 4) void rnn_fused(
    const float* __restrict__ inp, const float* __restrict__ b_in,
    const float* __restrict__ b_fc,
    const unsigned short* __restrict__ Bg, const float* __restrict__ bias,
    const unsigned short* __restrict__ Bin, const unsigned short* __restrict__ Bfc,
    float* __restrict__ out) {
    __shared__ __align__(16) unsigned short h_lds[2 * 8 * 4 * 64 * 8];   // 64KB dbuf
    unsigned short* in_alias = h_lds + 16384;   // buf1; dead once layer0 writes

    const int tid = threadIdx.x;
    const int lane = tid & 63;
    const int l15 = lane & 15;
    const int lq = lane >> 4;
    const int wid = tid >> 6;          // 0..15: wave owns feats wid*16..+15, all 64 steps
    const int row0 = blockIdx.x * BM;
    const int rdB = lq * 1024 + l15 * 16;   // one base for all B-role LDS reads

    // ---- stage input (64 x 63 fp32 -> bf16, K pad 64), [kk][lq][s][e] ----
    for (int idx = tid; idx < BM * 64; idx += THREADS) {
        int s = idx >> 6, k = idx & 63;
        float v = (k < DIO) ? inp[(size_t)(row0 + s) * DIO + k] : 0.f;
        int off = (k >> 5) * 4096 + ((k >> 3) & 3) * 1024 + s * 16 + (k & 7) * 2;
        *(unsigned short*)((char*)in_alias + off) = f2bf(v);
    }
    __syncthreads();

    // ---- input GEMM: x^T = W_in * inp^T + b_in -> buf0 ----
    {
        f32x4 acc[4];
        {
            f32x4 b4 = *(const f32x4*)(b_in + wid * 16 + lq * 4);
#pragma unroll
            for (int n = 0; n < 4; ++n) acc[n] = b4;
        }
        const bf16_8* __restrict__ pIA = (const bf16_8*)Bin + lane;
#pragma unroll
        for (int kk = 0; kk < 2; ++kk) {
            bf16_8 a = pIA[(wid * 2 + kk) * 64];
#pragma unroll
            for (int n = 0; n < 4; ++n) {
                bf16_8 b = *(const bf16_8*)((const char*)in_alias + rdB + kk * 4096 + n * 256);
                acc[n] = __builtin_amdgcn_mfma_f32_16x16x32_bf16(a, b, acc[n], 0, 0, 0);
            }
        }
        const int wrp = (wid >> 1) * 4096 + ((wid & 1) * 2 + (lq >> 1)) * 1024 +
                        l15 * 16 + (lq & 1) * 8;
#pragma unroll
        for (int n = 0; n < 4; ++n) {
            bf16_4 hv;
#pragma unroll
            for (int r = 0; r < 4; ++r) hv[r] = (__bf16)acc[n][r];
            *(bf16_4*)((char*)h_lds + wrp + n * 256) = hv;
        }
    }
    __syncthreads();

    // ---- 6 layers: one 16-feat pass per wave, 3 gates concurrent (12 chains) ----
    const char* Wb = (const char*)Bg + lane * 16;
    for (int l = 0; l < NL; ++l) {
        const char* cur = (const char*)h_lds + (l & 1) * 32768;
        char* nxt = (char*)h_lds + ((l + 1) & 1) * 32768;
        const char* pW = Wb + (size_t)(l * 16 + wid) * 24576;
        const float* pb = bias + l * 768 + wid * 16 + lq * 4;

        f32x4 ai[4], ag[4], ao[4];
        {
            f32x4 bi4 = *(const f32x4*)(pb);
            f32x4 bg4 = *(const f32x4*)(pb + 256);
            f32x4 bo4 = *(const f32x4*)(pb + 512);
#pragma unroll
            for (int n = 0; n < 4; ++n) { ai[n] = bi4; ag[n] = bg4; ao[n] = bo4; }
        }
#pragma unroll
        for (int kk = 0; kk < 8; ++kk) {
            bf16_8 wa = *(const bf16_8*)(pW + kk * 3072);
            bf16_8 wg = *(const bf16_8*)(pW + kk * 3072 + 1024);
            bf16_8 wo = *(const bf16_8*)(pW + kk * 3072 + 2048);
            bf16_8 b[4];
#pragma unroll
            for (int n = 0; n < 4; ++n)
                b[n] = *(const bf16_8*)(cur + rdB + kk * 4096 + n * 256);
#pragma unroll
            for (int n = 0; n < 4; ++n) {
                ai[n] = __builtin_amdgcn_mfma_f32_16x16x32_bf16(wa, b[n], ai[n], 0, 0, 0);
                ag[n] = __builtin_amdgcn_mfma_f32_16x16x32_bf16(wg, b[n], ag[n], 0, 0, 0);
                ao[n] = __builtin_amdgcn_mfma_f32_16x16x32_bf16(wo, b[n], ao[n], 0, 0, 0);
            }
        }
        act_write(nxt, wid, lq, l15, ai, ag, ao);
        __syncthreads();   // nxt published; cur free
    }

    // ---- final GEMM: out^T = W_fc * h^T + b_fc (buf0; all 16 waves) ----
    {
        const char* cur = (const char*)h_lds;
        const int ff = wid & 3;       // feature frag (16 feats)
        const int sf = wid >> 2;      // step frag (16 steps)
        f32x4 o4 = (f32x4){0.f, 0.f, 0.f, 0.f};
        const bf16_8* __restrict__ pF = (const bf16_8*)Bfc + lane;
#pragma unroll
        for (int kk = 0; kk < 8; ++kk) {
            bf16_8 a = pF[(ff * 8 + kk) * 64];
            bf16_8 b = *(const bf16_8*)(cur + rdB + kk * 4096 + sf * 256);
            o4 = __builtin_amdgcn_mfma_f32_16x16x32_bf16(a, b, o4, 0, 0, 0);
        }
        int s = row0 + sf * 16 + l15;
#pragma unroll
        for (int r = 0; r < 4; ++r) {
            int f = ff * 16 + lq * 4 + r;
            if (f < DIO) out[(size_t)s * DIO + f] = o4[r] + b_fc[f];
        }
    }
}

extern "C" void kernel_launch(void* const* d_in, const int* in_sizes, int n_in,
                              void* d_out, int out_size, void* d_ws, size_t ws_size,
                              hipStream_t stream) {
    const float* inputs = (const float*)d_in[0];
    const float* W_in   = (const float*)d_in[1];
    const float* b_in   = (const float*)d_in[2];
    const float* W_ih   = (const float*)d_in[3];
    // d_in[4] = W_hh: unused (h_prev == 0 every step)
    const float* b_ih   = (const float*)d_in[5];
    const float* b_hh   = (const float*)d_in[6];
    const float* W_fc   = (const float*)d_in[7];
    const float* b_fc   = (const float*)d_in[8];

    unsigned short* Bg  = (unsigned short*)d_ws;
    float* bias         = (float*)((char*)d_ws + (size_t)NBGF * 2);
    unsigned short* Bin = (unsigned short*)((char*)bias + (size_t)NBIAS * 4);
    unsigned short* Bfc = Bin + NBINF;

    int total = NBGF + NBIAS + NBINF + NBFCF;
    prep_kernel<<<(total + 255) / 256, 256, 0, stream>>>(W_in, W_ih, b_ih, b_hh, W_fc,
                                                         Bg, bias, Bin, Bfc);
    rnn_fused<<<STEPS / BM, THREADS, 0, stream>>>(inputs, b_in, b_fc, Bg, bias, Bin, Bfc,
                                                  (float*)d_out);
}